// Round 6
// baseline (149.836 us; speedup 1.0000x reference)
//
#include <hip/hip_runtime.h>
#include <hip/hip_bf16.h>
#include <cstdint>

// Problem constants (features: [512, 16, 512] fp32 -> N=8192 rows, D=512)
#define N_TOT 8192
#define DDIM  512
#define NBLK  64                       // 8192 / 128 tile blocks per dim
#define NTRI  (NBLK * (NBLK + 1) / 2)  // 2080 lower-triangle blocks
#define KITERS (DDIM / 64)             // 8
constexpr float INV_T = 1.0f / 0.07f;

typedef unsigned short u16;
typedef __attribute__((ext_vector_type(8))) short bf16x8_t;
typedef __attribute__((ext_vector_type(4))) float f32x4_t;

// ---- helpers ---------------------------------------------------------------

// fp32 -> bf16 bits, round-to-nearest-even
__device__ __forceinline__ u16 f2bf(float f) {
  uint32_t u = __float_as_uint(f);
  uint32_t r = (u + 0x7FFFu + ((u >> 16) & 1u)) >> 16;
  return (u16)r;
}

// async 16B global->LDS (global_load_lds_dwordx4). LDS dst is wave-uniform
// base + lane*16 (lane-contiguous) -- swizzle is applied to the GLOBAL src.
__device__ __forceinline__ void load16_to_lds(const void* g, void* l) {
  __builtin_amdgcn_global_load_lds(
      (const __attribute__((address_space(1))) unsigned int*)g,
      (__attribute__((address_space(3))) unsigned int*)l, 16, 0, 0);
}

// ---- kernel 1: row-normalize fp32 -> bf16 (+ zero tsum and out) ------------
__global__ __launch_bounds__(256) void normalize_kernel(const float* __restrict__ X,
                                                        u16* __restrict__ Xn,
                                                        float* __restrict__ tsum,
                                                        float* __restrict__ out) {
  if (blockIdx.x < 32) tsum[blockIdx.x * 256 + threadIdx.x] = 0.0f;
  if (blockIdx.x == 32 && threadIdx.x == 0) out[0] = 0.0f;
  const int lane = threadIdx.x & 63;
  const int row  = blockIdx.x * 4 + (threadIdx.x >> 6);
  const float4* xr = (const float4*)(X + (size_t)row * DDIM);
  float4 v0 = xr[lane];
  float4 v1 = xr[lane + 64];
  float s = v0.x * v0.x + v0.y * v0.y + v0.z * v0.z + v0.w * v0.w
          + v1.x * v1.x + v1.y * v1.y + v1.z * v1.z + v1.w * v1.w;
#pragma unroll
  for (int m = 1; m < 64; m <<= 1) s += __shfl_xor(s, m);
  const float scale = 1.0f / fmaxf(sqrtf(s), 1e-8f);
  ushort4 o0, o1;
  o0.x = f2bf(v0.x * scale); o0.y = f2bf(v0.y * scale);
  o0.z = f2bf(v0.z * scale); o0.w = f2bf(v0.w * scale);
  o1.x = f2bf(v1.x * scale); o1.y = f2bf(v1.y * scale);
  o1.z = f2bf(v1.z * scale); o1.w = f2bf(v1.w * scale);
  ushort4* orow = (ushort4*)(Xn + (size_t)row * DDIM);
  orow[lane]      = o0;
  orow[lane + 64] = o1;
}

// ---- kernel 2: lower-triangle tiles of C = Xn*Xn^T, fused exp row/col sums -
// 128x128 tile, BK=64, 256 threads = 4 waves in 2x2; each wave owns 64x64
// (4x4 frags of 16x16x32 bf16 MFMA). DOUBLE-BUFFERED LDS: prefetch for iter
// k+1 is issued AFTER the top-of-iter barrier, so the vmcnt(0) drain at the
// NEXT barrier happens a full compute phase later (~free). One barrier/iter.
// NO device-scope fences (R3: one __threadfence/block -> L2 wbl2/inv -> 3x).
// LDS XOR swizzle (R2-verified conflict-free): granule (row, j) j=0..7 stored
// at slot row*8 + (j ^ (row&7)); staging inverts the swizzle on the global src.
__global__ __launch_bounds__(256, 2) void gemm_exp_rowsum(const u16* __restrict__ Xn,
                                                          float* __restrict__ tsum) {
  __shared__ __align__(16) u16 sA[2][128 * 64];  // 2 x 16 KB
  __shared__ __align__(16) u16 sB[2][128 * 64];  // 2 x 16 KB

  // triangular decode: blockIdx.x -> (bi >= bj)
  const int k = blockIdx.x;
  int bi = (int)((sqrtf(8.0f * (float)k + 1.0f) - 1.0f) * 0.5f);
  while ((bi + 1) * (bi + 2) / 2 <= k) ++bi;
  while (bi * (bi + 1) / 2 > k) --bi;
  const int bj = k - bi * (bi + 1) / 2;
  const int rowBase = bi * 128;
  const int colBase = bj * 128;
  const bool isDiag = (bi == bj);

  const int t    = threadIdx.x;   // 0..255
  const int lane = t & 63;
  const int l15  = lane & 15;
  const int quad = lane >> 4;
  const int w    = t >> 6;        // 0..3
  const int wm   = w >> 1;        // 0..1: row offset wm*64
  const int wn   = w & 1;         // 0..1: col offset wn*64

  f32x4_t acc[4][4];
#pragma unroll
  for (int i = 0; i < 4; i++)
#pragma unroll
    for (int j = 0; j < 4; j++) acc[i][j] = {0.f, 0.f, 0.f, 0.f};

  // staging: per panel 1024 granules of 16B (128 rows x 8); thread t handles
  // granules t, t+256, t+512, t+768 -> rows srow, +32, +64, +96, same jlog
  // ((srow+32)&7 == srow&7).
  const int srow = t >> 3;
  const int jlog = ((t & 7) ^ (srow & 7)) * 8;
  const u16* gA = Xn + (size_t)(rowBase + srow) * DDIM + jlog;
  const u16* gB = Xn + (size_t)(colBase + srow) * DDIM + jlog;

  // prologue: stage tile 0 into buffer 0
#pragma unroll
  for (int r = 0; r < 4; r++) {
    load16_to_lds(gA + (size_t)(r * 32) * DDIM, &sA[0][t * 8 + r * 2048]);
    load16_to_lds(gB + (size_t)(r * 32) * DDIM, &sB[0][t * 8 + r * 2048]);
  }

#pragma unroll
  for (int it = 0; it < KITERS; ++it) {
    const int cur = it & 1;
    // barrier: waits for buffer[cur]'s loads (in flight since a full compute
    // phase ago, except it=0) and for all waves to finish reading buffer[cur]
    // from iteration it-2 before we overwrite it below.
    __syncthreads();

    if (it + 1 < KITERS) {
      const int nxt = (it + 1) & 1;
      const int k0 = (it + 1) * 64;
#pragma unroll
      for (int r = 0; r < 4; r++) {
        load16_to_lds(gA + (size_t)(r * 32) * DDIM + k0, &sA[nxt][t * 8 + r * 2048]);
        load16_to_lds(gB + (size_t)(r * 32) * DDIM + k0, &sB[nxt][t * 8 + r * 2048]);
      }
    }

#pragma unroll
    for (int kk = 0; kk < 2; kk++) {
      bf16x8_t a[4], b[4];
#pragma unroll
      for (int mi = 0; mi < 4; mi++) {
        const int row = wm * 64 + mi * 16 + l15;
        const int jp = (kk * 4 + quad) ^ (row & 7);
        a[mi] = *(const bf16x8_t*)&sA[cur][row * 64 + jp * 8];
      }
#pragma unroll
      for (int ni = 0; ni < 4; ni++) {
        const int row = wn * 64 + ni * 16 + l15;
        const int jp = (kk * 4 + quad) ^ (row & 7);
        b[ni] = *(const bf16x8_t*)&sB[cur][row * 64 + jp * 8];
      }
#pragma unroll
      for (int mi = 0; mi < 4; mi++)
#pragma unroll
        for (int ni = 0; ni < 4; ni++)
          acc[mi][ni] =
              __builtin_amdgcn_mfma_f32_16x16x32_bf16(a[mi], b[ni], acc[mi][ni], 0, 0, 0);
    }
  }

  // epilogue: e = exp((c-1)/T). C/D layout: col = lane&15, row = quad*4 + reg.
  if (isDiag) {
#pragma unroll
    for (int mi = 0; mi < 4; mi++) {
#pragma unroll
      for (int r = 0; r < 4; r++) {
        const int row = rowBase + wm * 64 + mi * 16 + quad * 4 + r;
        float rs = 0.0f;
#pragma unroll
        for (int ni = 0; ni < 4; ni++) {
          const int col = colBase + wn * 64 + ni * 16 + l15;
          const float e = __expf((acc[mi][ni][r] - 1.0f) * INV_T);
          rs += (row == col) ? 0.0f : e;
        }
        rs += __shfl_xor(rs, 1);
        rs += __shfl_xor(rs, 2);
        rs += __shfl_xor(rs, 4);
        rs += __shfl_xor(rs, 8);
        if (l15 == 0) atomicAdd(&tsum[row], rs);
      }
    }
  } else {
    float csum[4] = {0.f, 0.f, 0.f, 0.f};
#pragma unroll
    for (int mi = 0; mi < 4; mi++) {
#pragma unroll
      for (int r = 0; r < 4; r++) {
        const int row = rowBase + wm * 64 + mi * 16 + quad * 4 + r;
        float rs = 0.0f;
#pragma unroll
        for (int ni = 0; ni < 4; ni++) {
          const float e = __expf((acc[mi][ni][r] - 1.0f) * INV_T);
          rs += e;
          csum[ni] += e;
        }
        rs += __shfl_xor(rs, 1);
        rs += __shfl_xor(rs, 2);
        rs += __shfl_xor(rs, 4);
        rs += __shfl_xor(rs, 8);
        if (l15 == 0) atomicAdd(&tsum[row], rs);
      }
    }
#pragma unroll
    for (int ni = 0; ni < 4; ni++) {
      csum[ni] += __shfl_xor(csum[ni], 16);
      csum[ni] += __shfl_xor(csum[ni], 32);
      if (quad == 0) atomicAdd(&tsum[colBase + wn * 64 + ni * 16 + l15], csum[ni]);
    }
  }
}

// ---- kernel 3: loss = mean_i log1p(t_i), 32 blocks + atomic accumulate -----
__global__ __launch_bounds__(256) void finalize_kernel(const float* __restrict__ tsum,
                                                       float* __restrict__ out) {
  const int i = blockIdx.x * 256 + threadIdx.x;
  float s = log1pf(tsum[i]);
#pragma unroll
  for (int m = 1; m < 64; m <<= 1) s += __shfl_xor(s, m);
  __shared__ float ws[4];
  if ((threadIdx.x & 63) == 0) ws[threadIdx.x >> 6] = s;
  __syncthreads();
  if (threadIdx.x == 0)
    atomicAdd(out, (ws[0] + ws[1] + ws[2] + ws[3]) * (1.0f / N_TOT));
}

// ---- launcher --------------------------------------------------------------
extern "C" void kernel_launch(void* const* d_in, const int* in_sizes, int n_in,
                              void* d_out, int out_size, void* d_ws, size_t ws_size,
                              hipStream_t stream) {
  const float* X = (const float*)d_in[0];
  float* out = (float*)d_out;

  float* tsum = (float*)d_ws;                       // 8192 fp32 = 32 KB
  u16* Xn = (u16*)((char*)d_ws + 65536);            // 8192x512 bf16 = 8 MB

  normalize_kernel<<<N_TOT / 4, 256, 0, stream>>>(X, Xn, tsum, out);
  gemm_exp_rowsum<<<NTRI, 256, 0, stream>>>(Xn, tsum);
  finalize_kernel<<<N_TOT / 256, 256, 0, stream>>>(tsum, out);
}

// Round 7
// 133.454 us; speedup vs baseline: 1.1228x; 1.1228x over previous
//
#include <hip/hip_runtime.h>
#include <hip/hip_bf16.h>
#include <cstdint>

// Problem constants (features: [512, 16, 512] fp32 -> N=8192 rows, D=512)
#define N_TOT 8192
#define DDIM  512
#define NBLK  64                       // 8192 / 128 tile blocks per dim
#define NTRI  (NBLK * (NBLK + 1) / 2)  // 2080 lower-triangle blocks
constexpr float INV_T = 1.0f / 0.07f;

typedef unsigned short u16;
typedef __attribute__((ext_vector_type(8))) short bf16x8_t;
typedef __attribute__((ext_vector_type(4))) float f32x4_t;

// ---- helpers ---------------------------------------------------------------

// fp32 -> bf16 bits, round-to-nearest-even
__device__ __forceinline__ u16 f2bf(float f) {
  uint32_t u = __float_as_uint(f);
  uint32_t r = (u + 0x7FFFu + ((u >> 16) & 1u)) >> 16;
  return (u16)r;
}

// async 16B global->LDS (global_load_lds_dwordx4). LDS dst is wave-uniform
// base + lane*16 (lane-contiguous) -- swizzle is applied to the GLOBAL src.
__device__ __forceinline__ void load16_to_lds(const void* g, void* l) {
  __builtin_amdgcn_global_load_lds(
      (const __attribute__((address_space(1))) unsigned int*)g,
      (__attribute__((address_space(3))) unsigned int*)l, 16, 0, 0);
}

// ---- kernel 1: row-normalize fp32 -> bf16 (+ zero tsum and out) ------------
__global__ __launch_bounds__(256) void normalize_kernel(const float* __restrict__ X,
                                                        u16* __restrict__ Xn,
                                                        float* __restrict__ tsum,
                                                        float* __restrict__ out) {
  if (blockIdx.x < 32) tsum[blockIdx.x * 256 + threadIdx.x] = 0.0f;
  if (blockIdx.x == 32 && threadIdx.x == 0) out[0] = 0.0f;
  const int lane = threadIdx.x & 63;
  const int row  = blockIdx.x * 4 + (threadIdx.x >> 6);
  const float4* xr = (const float4*)(X + (size_t)row * DDIM);
  float4 v0 = xr[lane];
  float4 v1 = xr[lane + 64];
  float s = v0.x * v0.x + v0.y * v0.y + v0.z * v0.z + v0.w * v0.w
          + v1.x * v1.x + v1.y * v1.y + v1.z * v1.z + v1.w * v1.w;
#pragma unroll
  for (int m = 1; m < 64; m <<= 1) s += __shfl_xor(s, m);
  const float scale = 1.0f / fmaxf(sqrtf(s), 1e-8f);
  ushort4 o0, o1;
  o0.x = f2bf(v0.x * scale); o0.y = f2bf(v0.y * scale);
  o0.z = f2bf(v0.z * scale); o0.w = f2bf(v0.w * scale);
  o1.x = f2bf(v1.x * scale); o1.y = f2bf(v1.y * scale);
  o1.z = f2bf(v1.z * scale); o1.w = f2bf(v1.w * scale);
  ushort4* orow = (ushort4*)(Xn + (size_t)row * DDIM);
  orow[lane]      = o0;
  orow[lane + 64] = o1;
}

// ---- kernel 2: lower-triangle tiles of C = Xn*Xn^T, fused exp row/col sums -
// 128x128 tile, BK=64, 256 threads = 4 waves in 2x2; each wave owns 64x64
// (4x4 frags of 16x16x32 bf16 MFMA). Single-buffered 32 KB LDS (R5: dbuf/64KB
// regressed -- occupancy loss beats deferred drain). __launch_bounds__(256,4)
// caps regs at 128 -> 4 blocks/CU co-resident (K-loop live set ~111 regs).
// NO device-scope fences (R3: one __threadfence/block -> L2 wbl2/inv -> 3x).
// LDS XOR swizzle (R2-verified conflict-free): granule (row, j) j=0..7 stored
// at slot row*8 + (j ^ (row&7)); staging inverts the swizzle on the global src.
__global__ __launch_bounds__(256, 4) void gemm_exp_rowsum(const u16* __restrict__ Xn,
                                                          float* __restrict__ tsum) {
  __shared__ __align__(16) u16 sA[128 * 64];  // 16 KB
  __shared__ __align__(16) u16 sB[128 * 64];  // 16 KB

  // triangular decode: blockIdx.x -> (bi >= bj)
  const int k = blockIdx.x;
  int bi = (int)((sqrtf(8.0f * (float)k + 1.0f) - 1.0f) * 0.5f);
  while ((bi + 1) * (bi + 2) / 2 <= k) ++bi;
  while (bi * (bi + 1) / 2 > k) --bi;
  const int bj = k - bi * (bi + 1) / 2;
  const int rowBase = bi * 128;
  const int colBase = bj * 128;
  const bool isDiag = (bi == bj);

  const int t    = threadIdx.x;   // 0..255
  const int lane = t & 63;
  const int l15  = lane & 15;
  const int quad = lane >> 4;
  const int w    = t >> 6;        // 0..3
  const int wm   = w >> 1;        // 0..1: row offset wm*64
  const int wn   = w & 1;         // 0..1: col offset wn*64

  f32x4_t acc[4][4];
#pragma unroll
  for (int i = 0; i < 4; i++)
#pragma unroll
    for (int j = 0; j < 4; j++) acc[i][j] = {0.f, 0.f, 0.f, 0.f};

  // staging: per panel 1024 granules of 16B (128 rows x 8); thread t handles
  // granules t, t+256, t+512, t+768 -> rows srow, +32, +64, +96, same jlog
  // ((srow+32)&7 == srow&7).
  const int srow = t >> 3;
  const int jlog = ((t & 7) ^ (srow & 7)) * 8;
  const u16* gA = Xn + (size_t)(rowBase + srow) * DDIM + jlog;
  const u16* gB = Xn + (size_t)(colBase + srow) * DDIM + jlog;
  u16* lA = sA + t * 8;
  u16* lB = sB + t * 8;

  for (int k0 = 0; k0 < DDIM; k0 += 64) {
#pragma unroll
    for (int r = 0; r < 4; r++) {
      load16_to_lds(gA + (size_t)(r * 32) * DDIM + k0, lA + r * 256 * 8);
      load16_to_lds(gB + (size_t)(r * 32) * DDIM + k0, lB + r * 256 * 8);
    }
    __syncthreads();

#pragma unroll
    for (int kk = 0; kk < 2; kk++) {
      bf16x8_t a[4], b[4];
#pragma unroll
      for (int mi = 0; mi < 4; mi++) {
        const int row = wm * 64 + mi * 16 + l15;
        const int jp = (kk * 4 + quad) ^ (row & 7);
        a[mi] = *(const bf16x8_t*)&sA[row * 64 + jp * 8];
      }
#pragma unroll
      for (int ni = 0; ni < 4; ni++) {
        const int row = wn * 64 + ni * 16 + l15;
        const int jp = (kk * 4 + quad) ^ (row & 7);
        b[ni] = *(const bf16x8_t*)&sB[row * 64 + jp * 8];
      }
#pragma unroll
      for (int mi = 0; mi < 4; mi++)
#pragma unroll
        for (int ni = 0; ni < 4; ni++)
          acc[mi][ni] =
              __builtin_amdgcn_mfma_f32_16x16x32_bf16(a[mi], b[ni], acc[mi][ni], 0, 0, 0);
    }
    __syncthreads();
  }

  // epilogue: e = exp((c-1)/T). C/D layout: col = lane&15, row = quad*4 + reg.
  if (isDiag) {
#pragma unroll
    for (int mi = 0; mi < 4; mi++) {
#pragma unroll
      for (int r = 0; r < 4; r++) {
        const int row = rowBase + wm * 64 + mi * 16 + quad * 4 + r;
        float rs = 0.0f;
#pragma unroll
        for (int ni = 0; ni < 4; ni++) {
          const int col = colBase + wn * 64 + ni * 16 + l15;
          const float e = __expf((acc[mi][ni][r] - 1.0f) * INV_T);
          rs += (row == col) ? 0.0f : e;
        }
        rs += __shfl_xor(rs, 1);
        rs += __shfl_xor(rs, 2);
        rs += __shfl_xor(rs, 4);
        rs += __shfl_xor(rs, 8);
        if (l15 == 0) atomicAdd(&tsum[row], rs);
      }
    }
  } else {
    float csum[4] = {0.f, 0.f, 0.f, 0.f};
#pragma unroll
    for (int mi = 0; mi < 4; mi++) {
#pragma unroll
      for (int r = 0; r < 4; r++) {
        const int row = rowBase + wm * 64 + mi * 16 + quad * 4 + r;
        float rs = 0.0f;
#pragma unroll
        for (int ni = 0; ni < 4; ni++) {
          const float e = __expf((acc[mi][ni][r] - 1.0f) * INV_T);
          rs += e;
          csum[ni] += e;
        }
        rs += __shfl_xor(rs, 1);
        rs += __shfl_xor(rs, 2);
        rs += __shfl_xor(rs, 4);
        rs += __shfl_xor(rs, 8);
        if (l15 == 0) atomicAdd(&tsum[row], rs);
      }
    }
#pragma unroll
    for (int ni = 0; ni < 4; ni++) {
      csum[ni] += __shfl_xor(csum[ni], 16);
      csum[ni] += __shfl_xor(csum[ni], 32);
      if (quad == 0) atomicAdd(&tsum[colBase + wn * 64 + ni * 16 + l15], csum[ni]);
    }
  }
}

// ---- kernel 3: loss = mean_i log1p(t_i), 32 blocks + atomic accumulate -----
__global__ __launch_bounds__(256) void finalize_kernel(const float* __restrict__ tsum,
                                                       float* __restrict__ out) {
  const int i = blockIdx.x * 256 + threadIdx.x;
  float s = log1pf(tsum[i]);
#pragma unroll
  for (int m = 1; m < 64; m <<= 1) s += __shfl_xor(s, m);
  __shared__ float ws[4];
  if ((threadIdx.x & 63) == 0) ws[threadIdx.x >> 6] = s;
  __syncthreads();
  if (threadIdx.x == 0)
    atomicAdd(out, (ws[0] + ws[1] + ws[2] + ws[3]) * (1.0f / N_TOT));
}

// ---- launcher --------------------------------------------------------------
extern "C" void kernel_launch(void* const* d_in, const int* in_sizes, int n_in,
                              void* d_out, int out_size, void* d_ws, size_t ws_size,
                              hipStream_t stream) {
  const float* X = (const float*)d_in[0];
  float* out = (float*)d_out;

  float* tsum = (float*)d_ws;                       // 8192 fp32 = 32 KB
  u16* Xn = (u16*)((char*)d_ws + 65536);            // 8192x512 bf16 = 8 MB

  normalize_kernel<<<N_TOT / 4, 256, 0, stream>>>(X, Xn, tsum, out);
  gemm_exp_rowsum<<<NTRI, 256, 0, stream>>>(Xn, tsum);
  finalize_kernel<<<N_TOT / 256, 256, 0, stream>>>(tsum, out);
}

// Round 8
// 115.953 us; speedup vs baseline: 1.2922x; 1.1509x over previous
//
#include <hip/hip_runtime.h>
#include <hip/hip_bf16.h>
#include <cstdint>

// Problem constants (features: [512, 16, 512] fp32 -> N=8192 rows, D=512)
#define N_TOT 8192
#define DDIM  512
#define DBYTES 512                     // bytes per row in fp8
#define NBLK  64                       // 8192 / 128 tile blocks per dim
#define NTRI  (NBLK * (NBLK + 1) / 2)  // 2080 lower-triangle blocks
constexpr float INV_T = 1.0f / 0.07f;

typedef uint8_t u8;
typedef __attribute__((ext_vector_type(8))) int i32x8_t;
typedef __attribute__((ext_vector_type(4))) float f32x4_t;

// ---- helpers ---------------------------------------------------------------

// async 16B global->LDS (global_load_lds_dwordx4). LDS dst is wave-uniform
// base + lane*16 (lane-contiguous) -- swizzle is applied to the GLOBAL src.
__device__ __forceinline__ void load16_to_lds(const void* g, void* l) {
  __builtin_amdgcn_global_load_lds(
      (const __attribute__((address_space(1))) unsigned int*)g,
      (__attribute__((address_space(3))) unsigned int*)l, 16, 0, 0);
}

// ---- kernel 1: row-normalize fp32 -> fp8 e4m3 (+ zero tsum and out) --------
// one wave per row; hw cvt_pk_fp8 (RNE, OCP e4m3 on gfx950). |x|<=1 so no sat.
__global__ __launch_bounds__(256) void normalize_kernel(const float* __restrict__ X,
                                                        u8* __restrict__ Xn,
                                                        float* __restrict__ tsum,
                                                        float* __restrict__ out) {
  if (blockIdx.x < 32) tsum[blockIdx.x * 256 + threadIdx.x] = 0.0f;
  if (blockIdx.x == 32 && threadIdx.x == 0) out[0] = 0.0f;
  const int lane = threadIdx.x & 63;
  const int row  = blockIdx.x * 4 + (threadIdx.x >> 6);
  const float4* xr = (const float4*)(X + (size_t)row * DDIM);
  float4 v0 = xr[lane];       // elements 4*lane .. +3
  float4 v1 = xr[lane + 64];  // elements 256+4*lane .. +3
  float s = v0.x * v0.x + v0.y * v0.y + v0.z * v0.z + v0.w * v0.w
          + v1.x * v1.x + v1.y * v1.y + v1.z * v1.z + v1.w * v1.w;
#pragma unroll
  for (int m = 1; m < 64; m <<= 1) s += __shfl_xor(s, m);
  const float scale = 1.0f / fmaxf(sqrtf(s), 1e-8f);
  int w0 = __builtin_amdgcn_cvt_pk_fp8_f32(v0.x * scale, v0.y * scale, 0, 0);
  w0     = __builtin_amdgcn_cvt_pk_fp8_f32(v0.z * scale, v0.w * scale, w0, 1);
  int w1 = __builtin_amdgcn_cvt_pk_fp8_f32(v1.x * scale, v1.y * scale, 0, 0);
  w1     = __builtin_amdgcn_cvt_pk_fp8_f32(v1.z * scale, v1.w * scale, w1, 1);
  uint32_t* orow = (uint32_t*)(Xn + (size_t)row * DBYTES);
  orow[lane]      = (uint32_t)w0;   // bytes 4*lane .. +3
  orow[lane + 64] = (uint32_t)w1;   // bytes 256+4*lane .. +3
}

// ---- kernel 2: lower-triangle tiles of C = Xn*Xn^T, fused exp row/col sums -
// MX-fp8 path: 128x128 tile, BK=128 bytes (4 K-iters), 256 threads = 4 waves
// in 2x2; each wave owns 64x64 via 4x4 frags of mfma_scale 16x16x128 f8f6f4
// (cbsz=blgp=0 -> e4m3, unit E8M0 scales 0x7F). Single-buffered 32 KB LDS.
// NO device-scope fences (R3: one __threadfence/block -> L2 wbl2/inv -> 3x).
// LDS XOR swizzle (R2/R4-verified 0 conflicts): granule (row, j) j=0..7 (16B
// each) stored at slot row*8 + (j ^ (row&7)); staging inverts the swizzle on
// the global source address. Fragment = 32 B/lane = 2x ds_read_b128.
__global__ __launch_bounds__(256, 3) void gemm_exp_rowsum(const u8* __restrict__ Xn,
                                                          float* __restrict__ tsum) {
  __shared__ __align__(16) u8 sA[128 * 128];  // 16 KB
  __shared__ __align__(16) u8 sB[128 * 128];  // 16 KB

  // triangular decode: blockIdx.x -> (bi >= bj)
  const int k = blockIdx.x;
  int bi = (int)((sqrtf(8.0f * (float)k + 1.0f) - 1.0f) * 0.5f);
  while ((bi + 1) * (bi + 2) / 2 <= k) ++bi;
  while (bi * (bi + 1) / 2 > k) --bi;
  const int bj = k - bi * (bi + 1) / 2;
  const int rowBase = bi * 128;
  const int colBase = bj * 128;
  const bool isDiag = (bi == bj);

  const int t    = threadIdx.x;   // 0..255
  const int lane = t & 63;
  const int l15  = lane & 15;
  const int quad = lane >> 4;
  const int w    = t >> 6;        // 0..3
  const int wm   = w >> 1;        // 0..1: row offset wm*64
  const int wn   = w & 1;         // 0..1: col offset wn*64

  f32x4_t acc[4][4];
#pragma unroll
  for (int i = 0; i < 4; i++)
#pragma unroll
    for (int j = 0; j < 4; j++) acc[i][j] = {0.f, 0.f, 0.f, 0.f};

  // staging: per panel 1024 granules of 16B (128 rows x 8); thread t handles
  // granules t, t+256, t+512, t+768 -> rows srow, +32, +64, +96, same goff
  // ((srow+32)&7 == srow&7).
  const int srow = t >> 3;
  const int goff = ((t & 7) ^ (srow & 7)) * 16;  // swizzle-inverted byte offset
  const u8* gA = Xn + (size_t)(rowBase + srow) * DBYTES + goff;
  const u8* gB = Xn + (size_t)(colBase + srow) * DBYTES + goff;
  u8* lA = sA + t * 16;
  u8* lB = sB + t * 16;

  for (int k0 = 0; k0 < DBYTES; k0 += 128) {  // 4 iters
#pragma unroll
    for (int r = 0; r < 4; r++) {
      load16_to_lds(gA + (size_t)(r * 32) * DBYTES + k0, lA + r * 4096);
      load16_to_lds(gB + (size_t)(r * 32) * DBYTES + k0, lB + r * 4096);
    }
    __syncthreads();

    i32x8_t a[4], b[4];
#pragma unroll
    for (int mi = 0; mi < 4; mi++) {
      const int row = wm * 64 + mi * 16 + l15;
      const int s0 = ((quad * 2) ^ (row & 7)) * 16;
      const int s1 = ((quad * 2 + 1) ^ (row & 7)) * 16;
      int4 lo = *(const int4*)&sA[row * 128 + s0];
      int4 hi = *(const int4*)&sA[row * 128 + s1];
      a[mi] = (i32x8_t){lo.x, lo.y, lo.z, lo.w, hi.x, hi.y, hi.z, hi.w};
    }
#pragma unroll
    for (int ni = 0; ni < 4; ni++) {
      const int row = wn * 64 + ni * 16 + l15;
      const int s0 = ((quad * 2) ^ (row & 7)) * 16;
      const int s1 = ((quad * 2 + 1) ^ (row & 7)) * 16;
      int4 lo = *(const int4*)&sB[row * 128 + s0];
      int4 hi = *(const int4*)&sB[row * 128 + s1];
      b[ni] = (i32x8_t){lo.x, lo.y, lo.z, lo.w, hi.x, hi.y, hi.z, hi.w};
    }

#pragma unroll
    for (int mi = 0; mi < 4; mi++)
#pragma unroll
      for (int ni = 0; ni < 4; ni++)
        acc[mi][ni] = __builtin_amdgcn_mfma_scale_f32_16x16x128_f8f6f4(
            a[mi], b[ni], acc[mi][ni], 0, 0, 0, 0x7F7F7F7Fu, 0, 0x7F7F7F7Fu);
    __syncthreads();
  }

  // epilogue: e = exp((c-1)/T). C/D layout: col = lane&15, row = quad*4 + reg
  // (shape-determined, dtype-independent -- m121..m128).
  if (isDiag) {
#pragma unroll
    for (int mi = 0; mi < 4; mi++) {
#pragma unroll
      for (int r = 0; r < 4; r++) {
        const int row = rowBase + wm * 64 + mi * 16 + quad * 4 + r;
        float rs = 0.0f;
#pragma unroll
        for (int ni = 0; ni < 4; ni++) {
          const int col = colBase + wn * 64 + ni * 16 + l15;
          const float e = __expf((acc[mi][ni][r] - 1.0f) * INV_T);
          rs += (row == col) ? 0.0f : e;
        }
        rs += __shfl_xor(rs, 1);
        rs += __shfl_xor(rs, 2);
        rs += __shfl_xor(rs, 4);
        rs += __shfl_xor(rs, 8);
        if (l15 == 0) atomicAdd(&tsum[row], rs);
      }
    }
  } else {
    float csum[4] = {0.f, 0.f, 0.f, 0.f};
#pragma unroll
    for (int mi = 0; mi < 4; mi++) {
#pragma unroll
      for (int r = 0; r < 4; r++) {
        const int row = rowBase + wm * 64 + mi * 16 + quad * 4 + r;
        float rs = 0.0f;
#pragma unroll
        for (int ni = 0; ni < 4; ni++) {
          const float e = __expf((acc[mi][ni][r] - 1.0f) * INV_T);
          rs += e;
          csum[ni] += e;
        }
        rs += __shfl_xor(rs, 1);
        rs += __shfl_xor(rs, 2);
        rs += __shfl_xor(rs, 4);
        rs += __shfl_xor(rs, 8);
        if (l15 == 0) atomicAdd(&tsum[row], rs);
      }
    }
#pragma unroll
    for (int ni = 0; ni < 4; ni++) {
      csum[ni] += __shfl_xor(csum[ni], 16);
      csum[ni] += __shfl_xor(csum[ni], 32);
      if (quad == 0) atomicAdd(&tsum[colBase + wn * 64 + ni * 16 + l15], csum[ni]);
    }
  }
}

// ---- kernel 3: loss = mean_i log1p(t_i), 32 blocks + atomic accumulate -----
__global__ __launch_bounds__(256) void finalize_kernel(const float* __restrict__ tsum,
                                                       float* __restrict__ out) {
  const int i = blockIdx.x * 256 + threadIdx.x;
  float s = log1pf(tsum[i]);
#pragma unroll
  for (int m = 1; m < 64; m <<= 1) s += __shfl_xor(s, m);
  __shared__ float ws[4];
  if ((threadIdx.x & 63) == 0) ws[threadIdx.x >> 6] = s;
  __syncthreads();
  if (threadIdx.x == 0)
    atomicAdd(out, (ws[0] + ws[1] + ws[2] + ws[3]) * (1.0f / N_TOT));
}

// ---- launcher --------------------------------------------------------------
extern "C" void kernel_launch(void* const* d_in, const int* in_sizes, int n_in,
                              void* d_out, int out_size, void* d_ws, size_t ws_size,
                              hipStream_t stream) {
  const float* X = (const float*)d_in[0];
  float* out = (float*)d_out;

  float* tsum = (float*)d_ws;                       // 8192 fp32 = 32 KB
  u8* Xn = (u8*)d_ws + 65536;                       // 8192x512 fp8 = 4 MB

  normalize_kernel<<<N_TOT / 4, 256, 0, stream>>>(X, Xn, tsum, out);
  gemm_exp_rowsum<<<NTRI, 256, 0, stream>>>(Xn, tsum);
  finalize_kernel<<<N_TOT / 256, 256, 0, stream>>>(tsum, out);
}